// Round 1
// baseline (490.335 us; speedup 1.0000x reference)
//
#include <hip/hip_runtime.h>
#include <stdint.h>
#include <stddef.h>

using short8 = __attribute__((ext_vector_type(8))) short;
using short4v = __attribute__((ext_vector_type(4))) short;
using f32x4  = __attribute__((ext_vector_type(4))) float;
using bf16x8 = __attribute__((ext_vector_type(8))) __bf16;

#define DEVI __device__ __forceinline__

// round-to-nearest-even fp32 -> bf16 (bit pattern as short)
DEVI short bf16r(float f) {
  union { float f; uint32_t u; } x; x.f = f;
  uint32_t r = x.u + 0x7FFFu + ((x.u >> 16) & 1u);
  return (short)(r >> 16);
}

DEVI f32x4 mfma16(short8 a, short8 b, f32x4 c) {
  return __builtin_amdgcn_mfma_f32_16x16x32_bf16(
      __builtin_bit_cast(bf16x8, a), __builtin_bit_cast(bf16x8, b), c, 0, 0, 0);
}

DEVI void gload_lds16(const void* g, void* l) {
  __builtin_amdgcn_global_load_lds(
      (const void __attribute__((address_space(1)))*)g,
      (void __attribute__((address_space(3)))*)l,
      16, 0, 0);
}

// ---------------- fp32 -> bf16 conversion (weights) ----------------
__global__ void k_cvt(const float* __restrict__ src, short* __restrict__ dst, int n4) {
  int i = blockIdx.x * blockDim.x + threadIdx.x;
  if (i < n4) {
    f32x4 v = reinterpret_cast<const f32x4*>(src)[i];
    short4v o;
    o[0] = bf16r(v[0]); o[1] = bf16r(v[1]); o[2] = bf16r(v[2]); o[3] = bf16r(v[3]);
    reinterpret_cast<short4v*>(dst)[i] = o;
  }
}

// ---------------- GEMM: C(M,N) = (A(M,K) @ W(N,K)^T + bias) * alpha ----------------
// A: fp32 (reg-staged + converted) or bf16 (global_load_lds). W: bf16. 128x128 tile, BK=64.
template<bool A_F32, bool OUT_F32>
__global__ __launch_bounds__(256) void k_gemm(
    const void* __restrict__ Ap, const short* __restrict__ Bw,
    const float* __restrict__ bias, void* __restrict__ Cp,
    int M, int N, int K, float alpha)
{
  __shared__ short As[2][128 * 64];
  __shared__ short Bs[2][128 * 64];
  const int t = threadIdx.x;
  const int lane = t & 63;
  const int wid = t >> 6;
  const int wr = wid >> 1, wc = wid & 1;
  const int bm = blockIdx.y * 128;
  const int bn = blockIdx.x * 128;

  f32x4 acc[4][4];
  #pragma unroll
  for (int i = 0; i < 4; ++i)
    #pragma unroll
    for (int j = 0; j < 4; ++j) acc[i][j] = f32x4{0.f, 0.f, 0.f, 0.f};

  const int nt = K >> 6;

  // --- staging helpers ---
  auto stageB = [&](int buf, int k0) {
    #pragma unroll
    for (int i = 0; i < 4; ++i) {
      int lin = t * 16 + i * 4096;                 // linear byte dest in tile
      int a = lin ^ (((lin >> 7) & 7) << 4);       // pre-swizzled logical source
      int row = a >> 7;
      int col = (a & 127) >> 1;
      const short* g = Bw + (size_t)(bn + row) * K + k0 + col;
      gload_lds16(g, (char*)(&Bs[buf][0]) + (wid << 10) + (i << 12));
    }
  };
  auto stageA_bf16 = [&](int buf, int k0) {
    const short* A = (const short*)Ap;
    #pragma unroll
    for (int i = 0; i < 4; ++i) {
      int lin = t * 16 + i * 4096;
      int a = lin ^ (((lin >> 7) & 7) << 4);
      int row = a >> 7;
      int col = (a & 127) >> 1;
      const short* g = A + (size_t)(bm + row) * K + k0 + col;
      gload_lds16(g, (char*)(&As[buf][0]) + (wid << 10) + (i << 12));
    }
  };
  auto loadA_f32 = [&](int k0, float (&r)[4][8]) {
    const float* A = (const float*)Ap;
    #pragma unroll
    for (int i = 0; i < 4; ++i) {
      int idx = (t + i * 256) * 8;
      int row = idx >> 6;
      int col = idx & 63;
      const float* g = A + (size_t)(bm + row) * K + k0 + col;
      f32x4 v0 = *reinterpret_cast<const f32x4*>(g);
      f32x4 v1 = *reinterpret_cast<const f32x4*>(g + 4);
      r[i][0] = v0[0]; r[i][1] = v0[1]; r[i][2] = v0[2]; r[i][3] = v0[3];
      r[i][4] = v1[0]; r[i][5] = v1[1]; r[i][6] = v1[2]; r[i][7] = v1[3];
    }
  };
  auto writeA_f32 = [&](int buf, float (&r)[4][8]) {
    #pragma unroll
    for (int i = 0; i < 4; ++i) {
      int idx = (t + i * 256) * 8;
      int row = idx >> 6;
      int col = idx & 63;
      short8 s;
      #pragma unroll
      for (int e = 0; e < 8; ++e) s[e] = bf16r(r[i][e]);
      int byte = ((row << 7) + (col << 1)) ^ ((row & 7) << 4);
      *reinterpret_cast<short8*>((char*)(&As[buf][0]) + byte) = s;
    }
  };

  // prologue: stage tile 0
  if constexpr (A_F32) {
    float r0[4][8];
    loadA_f32(0, r0);
    writeA_f32(0, r0);
  } else {
    stageA_bf16(0, 0);
  }
  stageB(0, 0);
  __syncthreads();

  int cur = 0;
  for (int kt = 0; kt < nt; ++kt) {
    float ra[4][8];
    const bool pf = (kt + 1 < nt);
    if (pf) {
      if constexpr (A_F32) loadA_f32((kt + 1) << 6, ra);   // issue early (T14)
      else stageA_bf16(cur ^ 1, (kt + 1) << 6);
      stageB(cur ^ 1, (kt + 1) << 6);
    }
    // compute on buffer `cur`
    #pragma unroll
    for (int kk = 0; kk < 2; ++kk) {
      const int kb = (kk * 32 + ((lane >> 4) << 3)) << 1;  // k byte offset
      short8 af[4], bfr[4];
      #pragma unroll
      for (int i = 0; i < 4; ++i) {
        int row = wr * 64 + i * 16 + (lane & 15);
        int byte = ((row << 7) + kb) ^ ((row & 7) << 4);
        af[i] = *reinterpret_cast<const short8*>((const char*)(&As[cur][0]) + byte);
      }
      #pragma unroll
      for (int j = 0; j < 4; ++j) {
        int row = wc * 64 + j * 16 + (lane & 15);
        int byte = ((row << 7) + kb) ^ ((row & 7) << 4);
        bfr[j] = *reinterpret_cast<const short8*>((const char*)(&Bs[cur][0]) + byte);
      }
      #pragma unroll
      for (int i = 0; i < 4; ++i)
        #pragma unroll
        for (int j = 0; j < 4; ++j)
          acc[i][j] = mfma16(af[i], bfr[j], acc[i][j]);
    }
    if constexpr (A_F32) {
      if (pf) writeA_f32(cur ^ 1, ra);                      // write late (T14)
    }
    __syncthreads();
    cur ^= 1;
  }

  // epilogue
  #pragma unroll
  for (int j = 0; j < 4; ++j) {
    int col = bn + wc * 64 + j * 16 + (lane & 15);
    float bv = bias[col];
    #pragma unroll
    for (int i = 0; i < 4; ++i) {
      int row0 = bm + wr * 64 + i * 16 + ((lane >> 4) << 2);
      #pragma unroll
      for (int r = 0; r < 4; ++r) {
        float v = (acc[i][j][r] + bv) * alpha;
        if constexpr (OUT_F32)
          ((float*)Cp)[(size_t)(row0 + r) * N + col] = v;
        else
          ((short*)Cp)[(size_t)(row0 + r) * N + col] = bf16r(v);
      }
    }
  }
}

// ---------------- flash attention ----------------
// Q: (B,T,H,64) bf16 (pre-scaled by SCALE*log2e), K/V: (B,T,G,64) bf16, O: (B,T,H,64) bf16
__global__ __launch_bounds__(256) void k_attn(
    const short* __restrict__ Q, const short* __restrict__ Kt,
    const short* __restrict__ Vt, short* __restrict__ Op)
{
  constexpr int T = 2048;
  const int bh = blockIdx.x;          // 0..63
  const int b = bh >> 5, h = bh & 31;
  const int g = h >> 2;               // 4 heads per KV group
  const int q0 = blockIdx.y * 64;
  const int t = threadIdx.x, lane = t & 63, wid = t >> 6;

  __shared__ short Kl[2][64 * 72];    // [key][d], stride 72 (2-way conflicts = free)
  __shared__ short Vl[2][64 * 72];    // [d][key], stride 72 (transposed)
  __shared__ short Pl[4][16 * 72];    // per-wave P tile [q][key], stride 72

  // Q fragments: wave owns 16 q-rows; A-frag row = lane&15, k = (lane>>4)*8
  short8 qf[2];
  {
    const size_t rb = ((size_t)(b * T + q0 + wid * 16 + (lane & 15))) * 2048
                      + h * 64 + ((lane >> 4) << 3);
    qf[0] = *reinterpret_cast<const short8*>(Q + rb);
    qf[1] = *reinterpret_cast<const short8*>(Q + rb + 32);
  }

  float m[4], l[4];
  f32x4 o[4];
  #pragma unroll
  for (int r = 0; r < 4; ++r) { m[r] = -1e30f; l[r] = 0.f; }
  #pragma unroll
  for (int nf = 0; nf < 4; ++nf) o[nf] = f32x4{0.f, 0.f, 0.f, 0.f};

  short8 kreg[2], vreg[2];
  auto loadKV = [&](int kt0) {
    #pragma unroll
    for (int c = 0; c < 2; ++c) {
      int ch = t * 2 + c;
      int key = ch >> 3, d0 = (ch & 7) * 8;
      kreg[c] = *reinterpret_cast<const short8*>(
          Kt + ((size_t)(b * T + kt0 + key)) * 512 + g * 64 + d0);
    }
    int vkey = (t & 31) * 2, vd0 = (t >> 5) * 8;
    vreg[0] = *reinterpret_cast<const short8*>(
        Vt + ((size_t)(b * T + kt0 + vkey)) * 512 + g * 64 + vd0);
    vreg[1] = *reinterpret_cast<const short8*>(
        Vt + ((size_t)(b * T + kt0 + vkey + 1)) * 512 + g * 64 + vd0);
  };
  auto writeKV = [&](int buf) {
    #pragma unroll
    for (int c = 0; c < 2; ++c) {
      int ch = t * 2 + c;
      int key = ch >> 3, d0 = (ch & 7) * 8;
      *reinterpret_cast<short8*>(&Kl[buf][key * 72 + d0]) = kreg[c];
    }
    int vkey = (t & 31) * 2, vd0 = (t >> 5) * 8;
    #pragma unroll
    for (int e = 0; e < 8; ++e) {
      short2 pr; pr.x = vreg[0][e]; pr.y = vreg[1][e];
      *reinterpret_cast<short2*>(&Vl[buf][(vd0 + e) * 72 + vkey]) = pr;  // transpose
    }
  };

  loadKV(0);
  writeKV(0);
  __syncthreads();

  int cur = 0;
  const int NT = T / 64;
  for (int kt = 0; kt < NT; ++kt) {
    if (kt + 1 < NT) loadKV((kt + 1) * 64);   // issue global loads early

    // S = Q K^T  (C layout: key = lane&15, q-row = (lane>>4)*4 + reg)
    f32x4 s[4];
    #pragma unroll
    for (int kf = 0; kf < 4; ++kf) s[kf] = f32x4{0.f, 0.f, 0.f, 0.f};
    #pragma unroll
    for (int kk = 0; kk < 2; ++kk) {
      int dcol = kk * 32 + ((lane >> 4) << 3);
      #pragma unroll
      for (int kf = 0; kf < 4; ++kf) {
        short8 kb = *reinterpret_cast<const short8*>(
            &Kl[cur][(kf * 16 + (lane & 15)) * 72 + dcol]);
        s[kf] = mfma16(qf[kk], kb, s[kf]);
      }
    }

    // online softmax (scores already in log2 domain)
    #pragma unroll
    for (int r = 0; r < 4; ++r) {
      float v = fmaxf(fmaxf(s[0][r], s[1][r]), fmaxf(s[2][r], s[3][r]));
      v = fmaxf(v, __shfl_xor(v, 1));
      v = fmaxf(v, __shfl_xor(v, 2));
      v = fmaxf(v, __shfl_xor(v, 4));
      v = fmaxf(v, __shfl_xor(v, 8));
      float mn = fmaxf(m[r], v);
      float sc = exp2f(m[r] - mn);
      m[r] = mn;
      l[r] *= sc;
      #pragma unroll
      for (int nf = 0; nf < 4; ++nf) o[nf][r] *= sc;
      float acc = 0.f;
      #pragma unroll
      for (int kf = 0; kf < 4; ++kf) {
        float p = exp2f(s[kf][r] - mn);
        s[kf][r] = p;
        acc += p;
      }
      acc += __shfl_xor(acc, 1);
      acc += __shfl_xor(acc, 2);
      acc += __shfl_xor(acc, 4);
      acc += __shfl_xor(acc, 8);
      l[r] += acc;
    }

    // P -> LDS (bf16), per-wave private
    #pragma unroll
    for (int kf = 0; kf < 4; ++kf)
      #pragma unroll
      for (int r = 0; r < 4; ++r)
        Pl[wid][(((lane >> 4) << 2) + r) * 72 + kf * 16 + (lane & 15)] = bf16r(s[kf][r]);

    // O += P V   (A = P[q][key], B = V^T[d][key])
    #pragma unroll
    for (int kk = 0; kk < 2; ++kk) {
      int kcol = kk * 32 + ((lane >> 4) << 3);
      short8 pa = *reinterpret_cast<const short8*>(&Pl[wid][(lane & 15) * 72 + kcol]);
      #pragma unroll
      for (int nf = 0; nf < 4; ++nf) {
        short8 vb = *reinterpret_cast<const short8*>(
            &Vl[cur][(nf * 16 + (lane & 15)) * 72 + kcol]);
        o[nf] = mfma16(pa, vb, o[nf]);
      }
    }

    if (kt + 1 < NT) writeKV(cur ^ 1);   // write staged K/V late
    __syncthreads();
    cur ^= 1;
  }

  // epilogue: normalize, store bf16
  #pragma unroll
  for (int nf = 0; nf < 4; ++nf) {
    #pragma unroll
    for (int r = 0; r < 4; ++r) {
      int qrow = q0 + wid * 16 + ((lane >> 4) << 2) + r;
      int col = h * 64 + nf * 16 + (lane & 15);
      Op[(size_t)(b * T + qrow) * 2048 + col] = bf16r(o[nf][r] / l[r]);
    }
  }
}

// ---------------- launch ----------------
extern "C" void kernel_launch(void* const* d_in, const int* in_sizes, int n_in,
                              void* d_out, int out_size, void* d_ws, size_t ws_size,
                              hipStream_t stream)
{
  const float* query = (const float*)d_in[0];
  const float* key   = (const float*)d_in[1];
  const float* value = (const float*)d_in[2];
  const float* q_w   = (const float*)d_in[3];
  const float* q_b   = (const float*)d_in[4];
  const float* k_w   = (const float*)d_in[5];
  const float* k_b   = (const float*)d_in[6];
  const float* v_w   = (const float*)d_in[7];
  const float* v_b   = (const float*)d_in[8];
  const float* o_w   = (const float*)d_in[9];
  const float* o_b   = (const float*)d_in[10];
  float* out = (float*)d_out;

  char* ws = (char*)d_ws;
  short* q_wb = (short*)(ws);                  // 2048*2048*2 = 8388608 B
  short* k_wb = (short*)(ws + 8388608);        // 512*2048*2  = 2097152
  short* v_wb = (short*)(ws + 10485760);       // 2097152
  short* o_wb = (short*)(ws + 12582912);       // 8388608
  short* Qp   = (short*)(ws + 20971520);       // 4096*2048*2 = 16777216
  short* Kp   = (short*)(ws + 37748736);       // 4096*512*2  = 4194304
  short* Vp   = (short*)(ws + 41943040);       // 4194304
  short* Ap   = (short*)(ws + 46137344);       // 16777216  (end: 62914560 B)

  // convert weights to bf16 once per call
  k_cvt<<<4096, 256, 0, stream>>>(q_w, q_wb, 1048576);
  k_cvt<<<1024, 256, 0, stream>>>(k_w, k_wb, 262144);
  k_cvt<<<1024, 256, 0, stream>>>(v_w, v_wb, 262144);
  k_cvt<<<4096, 256, 0, stream>>>(o_w, o_wb, 1048576);

  // fold SCALE (hd^-0.5 = 0.125) and log2(e) into Q so softmax can use exp2
  const float ALPHA_Q = 0.125f * 1.4426950408889634f;

  k_gemm<true, false><<<dim3(16, 32), 256, 0, stream>>>(query, q_wb, q_b, Qp, 4096, 2048, 2048, ALPHA_Q);
  k_gemm<true, false><<<dim3(4, 32),  256, 0, stream>>>(key,   k_wb, k_b, Kp, 4096, 512,  2048, 1.0f);
  k_gemm<true, false><<<dim3(4, 32),  256, 0, stream>>>(value, v_wb, v_b, Vp, 4096, 512,  2048, 1.0f);

  k_attn<<<dim3(64, 32), 256, 0, stream>>>(Qp, Kp, Vp, Ap);

  k_gemm<false, true><<<dim3(16, 32), 256, 0, stream>>>(Ap, o_wb, o_b, out, 4096, 2048, 2048, 1.0f);
}

// Round 3
// 329.526 us; speedup vs baseline: 1.4880x; 1.4880x over previous
//
#include <hip/hip_runtime.h>
#include <stdint.h>
#include <stddef.h>

using short8 = __attribute__((ext_vector_type(8))) short;
using short4v = __attribute__((ext_vector_type(4))) short;
using f32x4  = __attribute__((ext_vector_type(4))) float;
using f32x16 = __attribute__((ext_vector_type(16))) float;
using bf16x8 = __attribute__((ext_vector_type(8))) __bf16;

#define DEVI __device__ __forceinline__

// round-to-nearest-even fp32 -> bf16 (bit pattern as short)
DEVI short bf16r(float f) {
  union { float f; uint32_t u; } x; x.f = f;
  uint32_t r = x.u + 0x7FFFu + ((x.u >> 16) & 1u);
  return (short)(r >> 16);
}

DEVI f32x4 mfma16(short8 a, short8 b, f32x4 c) {
  return __builtin_amdgcn_mfma_f32_16x16x32_bf16(
      __builtin_bit_cast(bf16x8, a), __builtin_bit_cast(bf16x8, b), c, 0, 0, 0);
}

DEVI f32x16 mfma32(short8 a, short8 b, f32x16 c) {
  return __builtin_amdgcn_mfma_f32_32x32x16_bf16(
      __builtin_bit_cast(bf16x8, a), __builtin_bit_cast(bf16x8, b), c, 0, 0, 0);
}

DEVI void gload_lds16(const void* g, void* l) {
  __builtin_amdgcn_global_load_lds(
      (const void __attribute__((address_space(1)))*)g,
      (void __attribute__((address_space(3)))*)l,
      16, 0, 0);
}

// v_exp_f32 computes 2^x
DEVI float fexp2(float x) {
  float r;
  asm("v_exp_f32 %0, %1" : "=v"(r) : "v"(x));
  return r;
}

// packed fp32->bf16: dst[15:0]=bf16(a), dst[31:16]=bf16(b)  [m214/T12-verified order]
DEVI unsigned cvtpk(float a, float b) {
  unsigned r;
  asm("v_cvt_pk_bf16_f32 %0, %1, %2" : "=v"(r) : "v"(a), "v"(b));
  return r;
}

// ---------------- fp32 -> bf16 conversion (weights) ----------------
__global__ void k_cvt(const float* __restrict__ src, short* __restrict__ dst, int n4) {
  int i = blockIdx.x * blockDim.x + threadIdx.x;
  if (i < n4) {
    f32x4 v = reinterpret_cast<const f32x4*>(src)[i];
    short4v o;
    o[0] = bf16r(v[0]); o[1] = bf16r(v[1]); o[2] = bf16r(v[2]); o[3] = bf16r(v[3]);
    reinterpret_cast<short4v*>(dst)[i] = o;
  }
}

// ---------------- GEMM: C(M,N) = (A(M,K) @ W(N,K)^T + bias) * alpha ----------------
template<bool A_F32, bool OUT_F32>
__global__ __launch_bounds__(256) void k_gemm(
    const void* __restrict__ Ap, const short* __restrict__ Bw,
    const float* __restrict__ bias, void* __restrict__ Cp,
    int M, int N, int K, float alpha)
{
  __shared__ short As[2][128 * 64];
  __shared__ short Bs[2][128 * 64];
  const int t = threadIdx.x;
  const int lane = t & 63;
  const int wid = t >> 6;
  const int wr = wid >> 1, wc = wid & 1;
  const int bm = blockIdx.y * 128;
  const int bn = blockIdx.x * 128;

  f32x4 acc[4][4];
  #pragma unroll
  for (int i = 0; i < 4; ++i)
    #pragma unroll
    for (int j = 0; j < 4; ++j) acc[i][j] = f32x4{0.f, 0.f, 0.f, 0.f};

  const int nt = K >> 6;

  auto stageB = [&](int buf, int k0) {
    #pragma unroll
    for (int i = 0; i < 4; ++i) {
      int lin = t * 16 + i * 4096;
      int a = lin ^ (((lin >> 7) & 7) << 4);
      int row = a >> 7;
      int col = (a & 127) >> 1;
      const short* g = Bw + (size_t)(bn + row) * K + k0 + col;
      gload_lds16(g, (char*)(&Bs[buf][0]) + (wid << 10) + (i << 12));
    }
  };
  auto stageA_bf16 = [&](int buf, int k0) {
    const short* A = (const short*)Ap;
    #pragma unroll
    for (int i = 0; i < 4; ++i) {
      int lin = t * 16 + i * 4096;
      int a = lin ^ (((lin >> 7) & 7) << 4);
      int row = a >> 7;
      int col = (a & 127) >> 1;
      const short* g = A + (size_t)(bm + row) * K + k0 + col;
      gload_lds16(g, (char*)(&As[buf][0]) + (wid << 10) + (i << 12));
    }
  };
  auto loadA_f32 = [&](int k0, float (&r)[4][8]) {
    const float* A = (const float*)Ap;
    #pragma unroll
    for (int i = 0; i < 4; ++i) {
      int idx = (t + i * 256) * 8;
      int row = idx >> 6;
      int col = idx & 63;
      const float* g = A + (size_t)(bm + row) * K + k0 + col;
      f32x4 v0 = *reinterpret_cast<const f32x4*>(g);
      f32x4 v1 = *reinterpret_cast<const f32x4*>(g + 4);
      r[i][0] = v0[0]; r[i][1] = v0[1]; r[i][2] = v0[2]; r[i][3] = v0[3];
      r[i][4] = v1[0]; r[i][5] = v1[1]; r[i][6] = v1[2]; r[i][7] = v1[3];
    }
  };
  auto writeA_f32 = [&](int buf, float (&r)[4][8]) {
    #pragma unroll
    for (int i = 0; i < 4; ++i) {
      int idx = (t + i * 256) * 8;
      int row = idx >> 6;
      int col = idx & 63;
      short8 s;
      #pragma unroll
      for (int e = 0; e < 8; ++e) s[e] = bf16r(r[i][e]);
      int byte = ((row << 7) + (col << 1)) ^ ((row & 7) << 4);
      *reinterpret_cast<short8*>((char*)(&As[buf][0]) + byte) = s;
    }
  };

  if constexpr (A_F32) {
    float r0[4][8];
    loadA_f32(0, r0);
    writeA_f32(0, r0);
  } else {
    stageA_bf16(0, 0);
  }
  stageB(0, 0);
  __syncthreads();

  int cur = 0;
  for (int kt = 0; kt < nt; ++kt) {
    float ra[4][8];
    const bool pf = (kt + 1 < nt);
    if (pf) {
      if constexpr (A_F32) loadA_f32((kt + 1) << 6, ra);
      else stageA_bf16(cur ^ 1, (kt + 1) << 6);
      stageB(cur ^ 1, (kt + 1) << 6);
    }
    #pragma unroll
    for (int kk = 0; kk < 2; ++kk) {
      const int kb = (kk * 32 + ((lane >> 4) << 3)) << 1;
      short8 af[4], bfr[4];
      #pragma unroll
      for (int i = 0; i < 4; ++i) {
        int row = wr * 64 + i * 16 + (lane & 15);
        int byte = ((row << 7) + kb) ^ ((row & 7) << 4);
        af[i] = *reinterpret_cast<const short8*>((const char*)(&As[cur][0]) + byte);
      }
      #pragma unroll
      for (int j = 0; j < 4; ++j) {
        int row = wc * 64 + j * 16 + (lane & 15);
        int byte = ((row << 7) + kb) ^ ((row & 7) << 4);
        bfr[j] = *reinterpret_cast<const short8*>((const char*)(&Bs[cur][0]) + byte);
      }
      #pragma unroll
      for (int i = 0; i < 4; ++i)
        #pragma unroll
        for (int j = 0; j < 4; ++j)
          acc[i][j] = mfma16(af[i], bfr[j], acc[i][j]);
    }
    if constexpr (A_F32) {
      if (pf) writeA_f32(cur ^ 1, ra);
    }
    __syncthreads();
    cur ^= 1;
  }

  #pragma unroll
  for (int j = 0; j < 4; ++j) {
    int col = bn + wc * 64 + j * 16 + (lane & 15);
    float bv = bias[col];
    #pragma unroll
    for (int i = 0; i < 4; ++i) {
      int row0 = bm + wr * 64 + i * 16 + ((lane >> 4) << 2);
      #pragma unroll
      for (int r = 0; r < 4; ++r) {
        float v = (acc[i][j][r] + bv) * alpha;
        if constexpr (OUT_F32)
          ((float*)Cp)[(size_t)(row0 + r) * N + col] = v;
        else
          ((short*)Cp)[(size_t)(row0 + r) * N + col] = bf16r(v);
      }
    }
  }
}

// ---------------- flash attention, 8-warp swapped-QK^T ----------------
// Q: (B,T,H*64) bf16 pre-scaled by SCALE*log2e. K/V: (B,T,G*64) bf16. O: (B,T,H*64) bf16.
// Per block: 256 q-rows (8 warps x 32), KVBLK=64, 32x32x16 MFMA.
// S^T = mfma(K, Q): col=q=lane&31 -> lane-local softmax state (m,l).
// PV swapped: O^T = mfma(V^T, P^T): col=q -> lane-local rescale/normalize.
// Cross-half (hi) exchange via __shfl_xor(.,32) — direction-proof (R2's
// inline-asm permlane32_swap direction assumption was the correctness bug).
__global__ __launch_bounds__(512) void k_attn(
    const short* __restrict__ Q, const short* __restrict__ Kg,
    const short* __restrict__ Vg, short* __restrict__ Op)
{
  constexpr int T = 2048;
  constexpr int NT = T / 64;

  // bijective XCD-chunked swizzle: 512 blocks -> 64 contiguous per XCD
  const int orig = blockIdx.x;
  const int wgid = (orig & 7) * 64 + (orig >> 3);
  const int bh = wgid >> 3;            // 0..63 = b*32+h
  const int qb = wgid & 7;
  const int b = bh >> 5, h = bh & 31;
  const int g = h >> 2;
  const int q0 = qb * 256;

  const int t = threadIdx.x;
  const int lane = t & 63;
  const int wid = t >> 6;
  const int lo = lane & 31;
  const int hi = lane >> 5;

  __shared__ alignas(16) union {
    struct {
      short Kl[2][64 * 64];   // [key][d], XOR-swizzled bytes, gload_lds staged
      short Vt[2][64 * 72];   // [d][key], stride 72, reg-staged transpose
    } s;
    short Ol[8][32 * 72];     // epilogue O transpose, per-warp
  } sm;

  // Q fragments (B-operand): lane holds Q[q0w+lo][s*16 + hi*8 .. +8]
  const size_t qrow = (size_t)(b * T + q0 + wid * 32 + lo);
  short8 qf[4];
  #pragma unroll
  for (int s = 0; s < 4; ++s)
    qf[s] = *reinterpret_cast<const short8*>(Q + qrow * 2048 + h * 64 + s * 16 + hi * 8);

  f32x16 o0, o1;
  #pragma unroll
  for (int r = 0; r < 16; ++r) { o0[r] = 0.f; o1[r] = 0.f; }
  float m = -10000.f, l = 0.f;

  const short* Kbase = Kg + (size_t)(b * T) * 512 + g * 64;
  const short* Vbase = Vg + (size_t)(b * T) * 512 + g * 64;

  auto stageK = [&](int buf, int k0) {
    int lin = t * 16;                            // linear LDS byte dest
    int a = lin ^ (((lin >> 7) & 7) << 4);       // inverse-swizzled logical src
    int row = a >> 7;
    int col = (a & 127) >> 1;
    gload_lds16(Kbase + (size_t)(k0 + row) * 512 + col,
                (char*)(&sm.s.Kl[buf][0]) + (wid << 10));
  };
  short8 vreg;
  auto loadV = [&](int k0) {
    // thread t: key=lane, d-chunk=wid*8 (16B per lane)
    vreg = *reinterpret_cast<const short8*>(
        Vbase + (size_t)(k0 + lane) * 512 + wid * 8);
  };
  auto writeV = [&](int buf) {
    // V^T[d][key]: lanes write consecutive keys -> conflict-free
    #pragma unroll
    for (int e = 0; e < 8; ++e)
      sm.s.Vt[buf][(wid * 8 + e) * 72 + lane] = vreg[e];
  };

  stageK(0, 0);
  loadV(0);
  writeV(0);
  __syncthreads();

  int cur = 0;
  for (int kt = 0; kt < NT; ++kt) {
    const bool pf = (kt + 1 < NT);
    if (pf) { stageK(cur ^ 1, (kt + 1) * 64); loadV((kt + 1) * 64); }

    // ---- K frags (A-operand) + QK^T ----
    short8 kf[2][4];
    #pragma unroll
    for (int tt = 0; tt < 2; ++tt)
      #pragma unroll
      for (int s = 0; s < 4; ++s) {
        int row = tt * 32 + lo;
        int byte = ((row << 7) + (s << 5) + (hi << 4)) ^ ((row & 7) << 4);
        kf[tt][s] = *reinterpret_cast<const short8*>((const char*)(&sm.s.Kl[cur][0]) + byte);
      }
    f32x16 st0, st1;
    #pragma unroll
    for (int r = 0; r < 16; ++r) { st0[r] = 0.f; st1[r] = 0.f; }
    #pragma unroll
    for (int s = 0; s < 4; ++s) {
      st0 = mfma32(kf[0][s], qf[s], st0);
      st1 = mfma32(kf[1][s], qf[s], st1);
    }

    // ---- online softmax (log2 domain), lane-local q ----
    float mx = st0[0];
    #pragma unroll
    for (int r = 1; r < 16; ++r) mx = fmaxf(mx, st0[r]);
    #pragma unroll
    for (int r = 0; r < 16; ++r) mx = fmaxf(mx, st1[r]);
    mx = fmaxf(mx, __shfl_xor(mx, 32));
    if (!__all(mx - m <= 8.0f)) {      // T13 defer-max
      float mn = fmaxf(m, mx);
      float sc = fexp2(m - mn);
      m = mn; l *= sc;
      o0 = o0 * sc; o1 = o1 * sc;
    }
    float ssum = 0.f;
    #pragma unroll
    for (int r = 0; r < 16; ++r) { float e = fexp2(st0[r] - m); st0[r] = e; ssum += e; }
    #pragma unroll
    for (int r = 0; r < 16; ++r) { float e = fexp2(st1[r] - m); st1[r] = e; ssum += e; }
    ssum += __shfl_xor(ssum, 32);
    l += ssum;

    // ---- P -> bf16 B-frags: cvt_pk + cross-half shfl_xor redistribution ----
    // target B-frag word w of pb[ks]: keys ks*16 + hi*8 + 2w, +2w+1 @ q=lo
    short8 pb[4];
    #pragma unroll
    for (int tt = 0; tt < 2; ++tt) {
      const f32x16& sv = tt ? st1 : st0;
      #pragma unroll
      for (int half = 0; half < 2; ++half) {
        unsigned x1 = cvtpk(sv[half * 8 + 0], sv[half * 8 + 1]);   // keys +0,+1 (+4hi)
        unsigned x2 = cvtpk(sv[half * 8 + 2], sv[half * 8 + 3]);   // keys +2,+3
        unsigned x3 = cvtpk(sv[half * 8 + 4], sv[half * 8 + 5]);   // keys +8,+9
        unsigned x4 = cvtpk(sv[half * 8 + 6], sv[half * 8 + 7]);   // keys +10,+11
        unsigned y1 = __shfl_xor(x1, 32);
        unsigned y2 = __shfl_xor(x2, 32);
        unsigned y3 = __shfl_xor(x3, 32);
        unsigned y4 = __shfl_xor(x4, 32);
        union { unsigned u[4]; short8 s8; } p;
        p.u[0] = hi ? y3 : x1;   // w0: keys +8hi+0,1
        p.u[1] = hi ? y4 : x2;   // w1: keys +8hi+2,3
        p.u[2] = hi ? x3 : y1;   // w2: keys +8hi+4,5
        p.u[3] = hi ? x4 : y2;   // w3: keys +8hi+6,7
        pb[tt * 2 + half] = p.s8;
      }
    }

    // ---- V^T frags (A-operand) + PV ----
    #pragma unroll
    for (int ks = 0; ks < 4; ++ks) {
      {
        int byte = (lo * 144) + (ks << 5) + (hi << 4);
        short8 va = *reinterpret_cast<const short8*>((const char*)(&sm.s.Vt[cur][0]) + byte);
        o0 = mfma32(va, pb[ks], o0);
      }
      {
        int byte = ((32 + lo) * 144) + (ks << 5) + (hi << 4);
        short8 va = *reinterpret_cast<const short8*>((const char*)(&sm.s.Vt[cur][0]) + byte);
        o1 = mfma32(va, pb[ks], o1);
      }
    }

    if (pf) writeV(cur ^ 1);
    __syncthreads();
    cur ^= 1;
  }

  // ---- epilogue: normalize, transpose via LDS, coalesced store ----
  float inv = 1.0f / l;
  #pragma unroll
  for (int dt = 0; dt < 2; ++dt) {
    const f32x16& ov = dt ? o1 : o0;
    #pragma unroll
    for (int r = 0; r < 16; r += 2) {
      unsigned d2 = cvtpk(ov[r] * inv, ov[r + 1] * inv);
      int dpos = dt * 32 + (r & 3) + 8 * (r >> 2) + 4 * hi;   // even
      *reinterpret_cast<unsigned*>((char*)(&sm.Ol[wid][0]) + (lo * 72 + dpos) * 2) = d2;
    }
  }
  __syncthreads();
  #pragma unroll
  for (int i = 0; i < 4; ++i) {
    int c = hi * 4 + i;
    short8 v = *reinterpret_cast<const short8*>((const char*)(&sm.Ol[wid][0]) + lo * 144 + c * 16);
    *reinterpret_cast<short8*>(Op + qrow * 2048 + h * 64 + c * 8) = v;
  }
}

// ---------------- launch ----------------
extern "C" void kernel_launch(void* const* d_in, const int* in_sizes, int n_in,
                              void* d_out, int out_size, void* d_ws, size_t ws_size,
                              hipStream_t stream)
{
  const float* query = (const float*)d_in[0];
  const float* key   = (const float*)d_in[1];
  const float* value = (const float*)d_in[2];
  const float* q_w   = (const float*)d_in[3];
  const float* q_b   = (const float*)d_in[4];
  const float* k_w   = (const float*)d_in[5];
  const float* k_b   = (const float*)d_in[6];
  const float* v_w   = (const float*)d_in[7];
  const float* v_b   = (const float*)d_in[8];
  const float* o_w   = (const float*)d_in[9];
  const float* o_b   = (const float*)d_in[10];
  float* out = (float*)d_out;

  char* ws = (char*)d_ws;
  short* q_wb = (short*)(ws);                  // 8388608 B
  short* k_wb = (short*)(ws + 8388608);        // 2097152
  short* v_wb = (short*)(ws + 10485760);       // 2097152
  short* o_wb = (short*)(ws + 12582912);       // 8388608
  short* Qp   = (short*)(ws + 20971520);       // 16777216
  short* Kp   = (short*)(ws + 37748736);       // 4194304
  short* Vp   = (short*)(ws + 41943040);       // 4194304
  short* Ap   = (short*)(ws + 46137344);       // 16777216

  k_cvt<<<4096, 256, 0, stream>>>(q_w, q_wb, 1048576);
  k_cvt<<<1024, 256, 0, stream>>>(k_w, k_wb, 262144);
  k_cvt<<<1024, 256, 0, stream>>>(v_w, v_wb, 262144);
  k_cvt<<<4096, 256, 0, stream>>>(o_w, o_wb, 1048576);

  // fold SCALE (0.125) and log2(e) into Q so softmax runs in exp2 domain
  const float ALPHA_Q = 0.125f * 1.4426950408889634f;

  k_gemm<true, false><<<dim3(16, 32), 256, 0, stream>>>(query, q_wb, q_b, Qp, 4096, 2048, 2048, ALPHA_Q);
  k_gemm<true, false><<<dim3(4, 32),  256, 0, stream>>>(key,   k_wb, k_b, Kp, 4096, 512,  2048, 1.0f);
  k_gemm<true, false><<<dim3(4, 32),  256, 0, stream>>>(value, v_wb, v_b, Vp, 4096, 512,  2048, 1.0f);

  k_attn<<<dim3(512), dim3(512), 0, stream>>>(Qp, Kp, Vp, Ap);

  k_gemm<false, true><<<dim3(16, 32), 256, 0, stream>>>(Ap, o_wb, o_b, out, 4096, 2048, 2048, 1.0f);
}